// Round 6
// baseline (334.558 us; speedup 1.0000x reference)
//
#include <hip/hip_runtime.h>

// out[s,n, l*4096 + i*64 + j] = norm_l(i,j) * sum_m c_l[s,n,m,i]*c_l[s,n,m,j]
// norm_l = (2l+1)^-1/2 off-diag, extra 3^-1/2 on diagonal.
// S*N = 24000 pairs, Q=64, output 1.57 GB fp32 -> write-BW bound.
// R6: wave-autonomous. One pair per WAVE (private 4KB LDS slice, no
// __syncthreads anywhere), PPW=5 pairs per wave with register prefetch
// (load p+1 issued before computing p), and u-inner/l-outer store order so
// each wave's writes are 1KB-per-instruction, fully sequential 320KB.

#define NTHREADS 256
#define PPW 5

typedef __attribute__((ext_vector_type(4))) float f32x4;

__global__ __launch_bounds__(NTHREADS) void ps_kernel(
    const float* __restrict__ c0, const float* __restrict__ c1,
    const float* __restrict__ c2, const float* __restrict__ c3,
    float* __restrict__ out, int total)
{
    // per-wave private slices: 4 waves x 2 buffers x 1024 floats = 32 KB
    __shared__ float lds[4][2][1024];

    const int t = threadIdx.x;
    const int w = t >> 6;
    const int lane = t & 63;

    const int p0 = (blockIdx.x * 4 + w) * PPW;
    if (p0 >= total) return;

    // ---- per-lane staging map: f32x4 index v = lane + 64k within the pair's
    // 1024 floats; regions (f32x4 units): [0,16)=c0, [16,64)=c1, [64,144)=c2,
    // [144,256)=c3. Keep 4 running source pointers, advance by stride per pair.
    const float* sp[4];
    int sstr[4];
    #pragma unroll
    for (int k = 0; k < 4; ++k) {
        const int v = lane + 64 * k;
        const float* base; int str; int off;
        if (v < 16)       { base = c0; str = 64;  off = v * 4;         }
        else if (v < 64)  { base = c1; str = 192; off = (v - 16) * 4;  }
        else if (v < 144) { base = c2; str = 320; off = (v - 64) * 4;  }
        else              { base = c3; str = 448; off = (v - 144) * 4; }
        sp[k] = base + (size_t)p0 * str + off;
        sstr[k] = str;
    }

    const int jq = lane & 15;     // column quad: j = 4jq .. 4jq+3
    const int i0 = lane >> 4;     // 0..3; row i = 4u + i0
    const int jbase = jq * 4;

    const float INV_SQRT3 = 0.57735026918962576f;
    const float CG[4] = {1.0f, 0.57735026918962576f, 0.44721359549995794f, 0.37796447300922720f};
    const int MOFF[4] = {0, 1, 4, 9};

    // diagonal hits this lane only at u == jq, component i0
    f32x4 dmask;
    dmask.x = (i0 == 0) ? INV_SQRT3 : 1.0f;
    dmask.y = (i0 == 1) ? INV_SQRT3 : 1.0f;
    dmask.z = (i0 == 2) ? INV_SQRT3 : 1.0f;
    dmask.w = (i0 == 3) ? INV_SQRT3 : 1.0f;

    f32x4* outv = reinterpret_cast<f32x4*>(out);

    // ---- prologue: load pair p0 into registers ----
    f32x4 nx0 = *reinterpret_cast<const f32x4*>(sp[0]);
    f32x4 nx1 = *reinterpret_cast<const f32x4*>(sp[1]);
    f32x4 nx2 = *reinterpret_cast<const f32x4*>(sp[2]);
    f32x4 nx3 = *reinterpret_cast<const f32x4*>(sp[3]);

    for (int q = 0; q < PPW; ++q) {
        const int p = p0 + q;
        if (p >= total) break;

        float* L = &lds[w][q & 1][0];
        // stage current pair into this wave's LDS slice (no barrier: private)
        *reinterpret_cast<f32x4*>(&L[(lane +   0) * 4]) = nx0;
        *reinterpret_cast<f32x4*>(&L[(lane +  64) * 4]) = nx1;
        *reinterpret_cast<f32x4*>(&L[(lane + 128) * 4]) = nx2;
        *reinterpret_cast<f32x4*>(&L[(lane + 192) * 4]) = nx3;

        // issue next pair's loads early — hide HBM latency under compute
        if (q + 1 < PPW && p + 1 < total) {
            nx0 = *reinterpret_cast<const f32x4*>(sp[0] + sstr[0] * (q + 1));
            nx1 = *reinterpret_cast<const f32x4*>(sp[1] + sstr[1] * (q + 1));
            nx2 = *reinterpret_cast<const f32x4*>(sp[2] + sstr[2] * (q + 1));
            nx3 = *reinterpret_cast<const f32x4*>(sp[3] + sstr[3] * (q + 1));
        }

        const size_t ob4 = (size_t)p * 4096;  // f32x4 index of this pair's output

        #pragma unroll
        for (int l = 0; l < 4; ++l) {
            const int nm = 2 * l + 1;
            const int moff = MOFF[l];
            const float cg = CG[l];

            f32x4 cj[7];
            #pragma unroll
            for (int m = 0; m < nm; ++m)
                cj[m] = (*reinterpret_cast<const f32x4*>(&L[(moff + m) * 64 + jbase])) * cg;

            #pragma unroll
            for (int u = 0; u < 16; ++u) {
                const int i = 4 * u + i0;
                f32x4 acc = {0.0f, 0.0f, 0.0f, 0.0f};
                #pragma unroll
                for (int m = 0; m < nm; ++m) {
                    const float ci = L[(moff + m) * 64 + i];  // broadcast in 16-lane group
                    acc += ci * cj[m];
                }
                if (jq == u) acc *= dmask;  // diagonal fix, one predicated mul
                // wave store = rows 4u..4u+3 x all 64 cols = 1KB contiguous;
                // sequential in u, then l, then pair -> 320KB/wave sequential
                outv[ob4 + (size_t)l * 1024 + (size_t)i * 16 + jq] = acc;
            }
        }
    }
}

extern "C" void kernel_launch(void* const* d_in, const int* in_sizes, int n_in,
                              void* d_out, int out_size, void* d_ws, size_t ws_size,
                              hipStream_t stream) {
    const float* c0 = (const float*)d_in[0];
    const float* c1 = (const float*)d_in[1];
    const float* c2 = (const float*)d_in[2];
    const float* c3 = (const float*)d_in[3];
    float* out = (float*)d_out;

    const int total = in_sizes[0] / 64;          // S*N pairs (c0 is (S,N,1,64))
    const int grid = (total + 4 * PPW - 1) / (4 * PPW);

    ps_kernel<<<dim3(grid), dim3(NTHREADS), 0, stream>>>(c0, c1, c2, c3, out, total);
}